// Round 9
// baseline (694.370 us; speedup 1.0000x reference)
//
#include <hip/hip_runtime.h>
#include <hip/hip_fp16.h>
#include <math.h>

constexpr int NNODES  = 102400;
constexpr int NEDGES  = 409600;
constexpr int NGRAPHS = 2048;
constexpr int HIDDEN  = 128;

typedef __attribute__((ext_vector_type(8))) _Float16 f16x8;
typedef __attribute__((ext_vector_type(4))) float f32x4;
typedef __attribute__((ext_vector_type(4))) unsigned short us4;

__device__ __forceinline__ float relu_f(float v) { return fmaxf(v, 0.0f); }
__device__ __forceinline__ float h2f(unsigned short s) {
  return (float)__builtin_bit_cast(_Float16, s);
}
__device__ __forceinline__ unsigned short f2h(float x) {
  return __builtin_bit_cast(unsigned short, (_Float16)x);
}
// 2-way f16 split with scaled lo plane: x ~= hi + lo * 2^-11
__device__ __forceinline__ void split2h(float x, _Float16& h, _Float16& l) {
  h = (_Float16)x;
  float r = x - (float)h;
  l = (_Float16)(r * 2048.0f);
}

// ---------------- prep: histograms + weight-split + x_lig->f16(80) ----------------
__global__ void prep_kernel(const int* __restrict__ ei, const int* __restrict__ batch,
                            int* __restrict__ counts, int* __restrict__ gcounts,
                            const float* __restrict__ W10, const float* __restrict__ W20,
                            const float* __restrict__ W11, const float* __restrict__ W21,
                            const float* __restrict__ W12, const float* __restrict__ W22,
                            short* __restrict__ ws,
                            const float* __restrict__ xlig, unsigned short* __restrict__ Ylig) {
  int b = blockIdx.x;
  if (b < NEDGES / 256) {
    atomicAdd(&counts[ei[NEDGES + b * 256 + threadIdx.x]], 1);
    return;
  }
  if (b < NEDGES / 256 + NNODES / 256) {
    atomicAdd(&gcounts[batch[(b - NEDGES / 256) * 256 + threadIdx.x]], 1);
    return;
  }
  if (b < NEDGES / 256 + NNODES / 256 + 736) {
    int bw = b - (NEDGES / 256 + NNODES / 256);
    int n = threadIdx.x;
    if (n >= 128) return;
    const float* src; long base; int k, realK, KP;
    if (bw < 96) {
      src = W10; base = 0; k = bw; realK = 78; KP = 96;
    } else {
      int q = bw - 96;
      int mat = q >> 7;
      k = q & 127; realK = 128; KP = 128;
      const float* srcs[5] = {W20, W11, W21, W12, W22};
      const long bases[5] = {24576, 57344, 90112, 122880, 155648};
      src = srcs[mat]; base = bases[mat];
    }
    float x = (k < realK) ? src[k * 128 + n] : 0.0f;
    _Float16 h, l;
    split2h(x, h, l);
    long e = base + ((long)(k >> 5) * 128 + n) * 32 + (k & 31);
    long ps = (long)KP * 128;
    ws[e] = __builtin_bit_cast(short, h);
    ws[e + ps] = __builtin_bit_cast(short, l);
    return;
  }
  // x_lig -> f16, padded 78 -> 80
  const int xi = (b - (NEDGES / 256 + NNODES / 256 + 736)) * 256 + threadIdx.x;
  const int row = xi / 20, qc = (xi - row * 20) * 4;
  if (row < NNODES) {
    us4 o;
#pragma unroll
    for (int c = 0; c < 4; ++c) {
      const int col = qc + c;
      o[c] = (col < 78) ? f2h(xlig[(size_t)row * 78 + col]) : (unsigned short)0;
    }
    *(us4*)&Ylig[(size_t)row * 80 + qc] = o;
  }
}

// ---------------- merged scans ----------------
__device__ __forceinline__ void scan_block_body(const int* in, int n, int* out_excl,
                                                int* bsums, int lb) {
  __shared__ int s[256];
  int t = threadIdx.x;
  int i = lb * 256 + t;
  int v = (i < n) ? in[i] : 0;
  s[t] = v;
  __syncthreads();
  for (int off = 1; off < 256; off <<= 1) {
    int x = (t >= off) ? s[t - off] : 0;
    __syncthreads();
    s[t] += x;
    __syncthreads();
  }
  if (i < n) out_excl[i] = s[t] - v;
  if (t == 255) bsums[lb] = s[255];
}

__global__ void scan_block2_kernel(const int* __restrict__ counts, int* __restrict__ row_ptr,
                                   int* __restrict__ bsumsA, const int* __restrict__ gcounts,
                                   int* __restrict__ gptr, int* __restrict__ bsumsB) {
  int b = blockIdx.x;
  if (b < NNODES / 256) scan_block_body(counts, NNODES, row_ptr, bsumsA, b);
  else scan_block_body(gcounts, NGRAPHS, gptr, bsumsB, b - NNODES / 256);
}

__global__ void scan_top2_kernel(int* __restrict__ bsumsA, int* __restrict__ bsumsB) {
  __shared__ int s[1024];
  int* bs = (blockIdx.x == 0) ? bsumsA : bsumsB;
  int nb  = (blockIdx.x == 0) ? (NNODES / 256) : (NGRAPHS / 256);
  int t = threadIdx.x;
  int v = (t < nb) ? bs[t] : 0;
  s[t] = v;
  __syncthreads();
  for (int off = 1; off < 1024; off <<= 1) {
    int x = (t >= off) ? s[t - off] : 0;
    __syncthreads();
    s[t] += x;
    __syncthreads();
  }
  if (t < nb) bs[t] = s[t] - v;
  if (t == 1023) bs[nb] = s[1023];
}

__global__ void scan_add2_kernel(int* __restrict__ row_ptr, const int* __restrict__ bsumsA,
                                 int* __restrict__ nxt, int* __restrict__ gptr,
                                 const int* __restrict__ bsumsB) {
  int b = blockIdx.x, t = threadIdx.x;
  if (b < NNODES / 256) {
    int i = b * 256 + t;
    int v = row_ptr[i] + bsumsA[b];
    row_ptr[i] = v;
    nxt[i] = v;
    if (i == 0) row_ptr[NNODES] = bsumsA[NNODES / 256];
  } else {
    int lb = b - NNODES / 256;
    int i = lb * 256 + t;
    gptr[i] += bsumsB[lb];
    if (i == 0) gptr[NGRAPHS] = bsumsB[NGRAPHS / 256];
  }
}

__global__ void scatter_kernel(const int* __restrict__ ei, int* __restrict__ nxt,
                               int* __restrict__ csr_src) {
  int e = blockIdx.x * blockDim.x + threadIdx.x;
  if (e < NEDGES) {
    int s = ei[e];
    int d = ei[NEDGES + e];
    int pos = atomicAdd(&nxt[d], 1);
    csr_src[pos] = s;
  }
}

// ---------------- GIN block body ----------------
// Gather (R0 structure): depth-2 software-pipelined edge stream per slot.
// All layers: f16 rows (us4/lane) — layer 0 from Ylig (YSTR=80, KP=96,
// quads >= 20 zero-fill padding), layers 1/2 from Oh (YSTR=128) with
// BN+ReLU on consume. MFMA mm1/mm2 via f16x2 split. O stored raw f16.
constexpr int STRK = 132;
template<int YSTR, int KP1, bool XF>
__device__ __forceinline__ void gin_block(
    int bid, const unsigned short* __restrict__ Xh,
    unsigned short* __restrict__ OhOut,
    const int* __restrict__ row_ptr, const int* __restrict__ csr_src,
    const short* __restrict__ w1s, const float* __restrict__ b1,
    const short* __restrict__ w2s, const float* __restrict__ b2,
    const float* __restrict__ psum, const float* __restrict__ psq,
    const float* __restrict__ bg, const float* __restrict__ bb2,
    float* __restrict__ bn_sum, float* __restrict__ bn_sq,
    float* buf) {
  const int t = threadIdx.x;
  const int wv = t >> 6, lane = t & 63;
  const int base = bid * 32;

  // ---- f16 gather, depth-2 pipelined: lane = (row-half, feature-quad)
  {
    const int q = lane & 31, half = lane >> 5;
    const int f = 4 * q;
    const bool fa = (f < YSTR);
    float sc[4] = {1.f, 1.f, 1.f, 1.f}, sh[4] = {0.f, 0.f, 0.f, 0.f};
    if (XF) {
#pragma unroll
      for (int c = 0; c < 4; ++c) {
        float mu = psum[f + c] * (1.0f / NNODES);
        float va = fmaxf(psq[f + c] * (1.0f / NNODES) - mu * mu, 0.0f);
        sc[c] = bg[f + c] / sqrtf(va + 1e-5f);
        sh[c] = bb2[f + c] - mu * sc[c];
      }
    }
    float4 acc[4];
    us4 u0[4];
    int e[4], eend[4], i0[4], i1[4];
#pragma unroll
    for (int p = 0; p < 4; ++p) {
      const int node = base + wv * 8 + 2 * p + half;
      e[p] = row_ptr[node];
      eend[p] = row_ptr[node + 1];
      acc[p] = make_float4(0.f, 0.f, 0.f, 0.f);
      if (fa) {
        const us4 s = *(const us4*)&Xh[(size_t)node * YSTR + f];
        if (XF) {
          acc[p].x = relu_f(fmaf(h2f(s[0]), sc[0], sh[0]));
          acc[p].y = relu_f(fmaf(h2f(s[1]), sc[1], sh[1]));
          acc[p].z = relu_f(fmaf(h2f(s[2]), sc[2], sh[2]));
          acc[p].w = relu_f(fmaf(h2f(s[3]), sc[3], sh[3]));
        } else {
          acc[p] = make_float4(h2f(s[0]), h2f(s[1]), h2f(s[2]), h2f(s[3]));
        }
      }
      i0[p] = (e[p] < eend[p]) ? csr_src[e[p]] : -1;
      i1[p] = (e[p] + 1 < eend[p]) ? csr_src[e[p] + 1] : -1;
    }
#pragma unroll
    for (int p = 0; p < 4; ++p)
      if (fa && i0[p] >= 0) u0[p] = *(const us4*)&Xh[(size_t)i0[p] * YSTR + f];
    bool any = (i0[0] >= 0) || (i0[1] >= 0) || (i0[2] >= 0) || (i0[3] >= 0);
    while (any) {
      us4 u1[4];
      int i2[4];
#pragma unroll
      for (int p = 0; p < 4; ++p)
        if (fa && i1[p] >= 0) u1[p] = *(const us4*)&Xh[(size_t)i1[p] * YSTR + f];
#pragma unroll
      for (int p = 0; p < 4; ++p)
        i2[p] = (e[p] + 2 < eend[p]) ? csr_src[e[p] + 2] : -1;
      any = false;
#pragma unroll
      for (int p = 0; p < 4; ++p) {
        if (fa && i0[p] >= 0) {
          if (XF) {
            acc[p].x += relu_f(fmaf(h2f(u0[p][0]), sc[0], sh[0]));
            acc[p].y += relu_f(fmaf(h2f(u0[p][1]), sc[1], sh[1]));
            acc[p].z += relu_f(fmaf(h2f(u0[p][2]), sc[2], sh[2]));
            acc[p].w += relu_f(fmaf(h2f(u0[p][3]), sc[3], sh[3]));
          } else {
            acc[p].x += h2f(u0[p][0]); acc[p].y += h2f(u0[p][1]);
            acc[p].z += h2f(u0[p][2]); acc[p].w += h2f(u0[p][3]);
          }
        }
        ++e[p];
        i0[p] = i1[p]; i1[p] = i2[p]; u0[p] = u1[p];
        any = any || (i0[p] >= 0);
      }
    }
#pragma unroll
    for (int p = 0; p < 4; ++p)
      if (f < KP1)
        *(float4*)&buf[(wv * 8 + 2 * p + half) * STRK + f] = acc[p];
  }
  __syncthreads();

  const int rb = wv & 1, nbase = (wv >> 1) * 64;
  const int l15 = lane & 15, quad = lane >> 4;
  const int aoff = (rb * 16 + l15) * STRK;
  constexpr int PS1 = KP1 * 128;
  constexpr int PS2 = 128 * 128;
  constexpr float INVL = 1.0f / 2048.0f;

  // ---- mm1 (MFMA f16x2)
  f32x4 am1[4] = {}, ac1[4] = {};
  for (int ks = 0; ks < KP1 / 32; ++ks) {
    const int k0 = ks * 32;
    const float4 xa = *(const float4*)&buf[aoff + k0 + quad * 8];
    const float4 xb = *(const float4*)&buf[aoff + k0 + quad * 8 + 4];
    f16x8 Ah, Al;
    {
      const float xv[8] = {xa.x, xa.y, xa.z, xa.w, xb.x, xb.y, xb.z, xb.w};
#pragma unroll
      for (int j = 0; j < 8; ++j) {
        _Float16 h, l;
        split2h(xv[j], h, l);
        Ah[j] = h; Al[j] = l;
      }
    }
    f16x8 Bh[4], Bl[4];
#pragma unroll
    for (int ct = 0; ct < 4; ++ct) {
      const int n = nbase + ct * 16 + l15;
      const short* wp = w1s + ((long)(ks * 128 + n) << 5) + (quad << 3);
      Bh[ct] = *(const f16x8*)(wp);
      Bl[ct] = *(const f16x8*)(wp + PS1);
    }
#pragma unroll
    for (int ct = 0; ct < 4; ++ct) ac1[ct] = __builtin_amdgcn_mfma_f32_16x16x32_f16(Ah, Bl[ct], ac1[ct], 0, 0, 0);
#pragma unroll
    for (int ct = 0; ct < 4; ++ct) ac1[ct] = __builtin_amdgcn_mfma_f32_16x16x32_f16(Al, Bh[ct], ac1[ct], 0, 0, 0);
#pragma unroll
    for (int ct = 0; ct < 4; ++ct) am1[ct] = __builtin_amdgcn_mfma_f32_16x16x32_f16(Ah, Bh[ct], am1[ct], 0, 0, 0);
  }
  __syncthreads();

  // mid = relu(am + ac/2048 + b1), stored [m][j]
#pragma unroll
  for (int ct = 0; ct < 4; ++ct) {
    const int n = nbase + ct * 16 + l15;
    const float bb = b1[n];
#pragma unroll
    for (int reg = 0; reg < 4; ++reg) {
      const int m = rb * 16 + quad * 4 + reg;
      buf[m * STRK + n] = relu_f(fmaf(ac1[ct][reg], INVL, am1[ct][reg]) + bb);
    }
  }
  __syncthreads();

  // ---- mm2 (MFMA f16x2)
  f32x4 am2[4] = {}, ac2[4] = {};
  for (int ks = 0; ks < 4; ++ks) {
    const int k0 = ks * 32;
    const float4 xa = *(const float4*)&buf[aoff + k0 + quad * 8];
    const float4 xb = *(const float4*)&buf[aoff + k0 + quad * 8 + 4];
    f16x8 Ah, Al;
    {
      const float xv[8] = {xa.x, xa.y, xa.z, xa.w, xb.x, xb.y, xb.z, xb.w};
#pragma unroll
      for (int j = 0; j < 8; ++j) {
        _Float16 h, l;
        split2h(xv[j], h, l);
        Ah[j] = h; Al[j] = l;
      }
    }
    f16x8 Bh[4], Bl[4];
#pragma unroll
    for (int ct = 0; ct < 4; ++ct) {
      const int n = nbase + ct * 16 + l15;
      const short* wp = w2s + ((long)(ks * 128 + n) << 5) + (quad << 3);
      Bh[ct] = *(const f16x8*)(wp);
      Bl[ct] = *(const f16x8*)(wp + PS2);
    }
#pragma unroll
    for (int ct = 0; ct < 4; ++ct) ac2[ct] = __builtin_amdgcn_mfma_f32_16x16x32_f16(Ah, Bl[ct], ac2[ct], 0, 0, 0);
#pragma unroll
    for (int ct = 0; ct < 4; ++ct) ac2[ct] = __builtin_amdgcn_mfma_f32_16x16x32_f16(Al, Bh[ct], ac2[ct], 0, 0, 0);
#pragma unroll
    for (int ct = 0; ct < 4; ++ct) am2[ct] = __builtin_amdgcn_mfma_f32_16x16x32_f16(Ah, Bh[ct], am2[ct], 0, 0, 0);
  }

  // epilogue: Oh (f16) + BN stats
  float cs[4], cq[4];
#pragma unroll
  for (int ct = 0; ct < 4; ++ct) {
    const int n = nbase + ct * 16 + l15;
    const float bb = b2[n];
    float s = 0.f, q = 0.f;
#pragma unroll
    for (int reg = 0; reg < 4; ++reg) {
      const int m = rb * 16 + quad * 4 + reg;
      const float o = fmaf(ac2[ct][reg], INVL, am2[ct][reg]) + bb;
      OhOut[(size_t)(base + m) * HIDDEN + n] = f2h(o);
      s += o;
      q = fmaf(o, o, q);
    }
    cs[ct] = s; cq[ct] = q;
  }
  __syncthreads();
  const int g = rb * 4 + quad;
#pragma unroll
  for (int ct = 0; ct < 4; ++ct) {
    const int n = nbase + ct * 16 + l15;
    buf[n * 8 + g] = cs[ct];
    buf[1024 + n * 8 + g] = cq[ct];
  }
  __syncthreads();
  if (t < HIDDEN) {
    float s = 0.f, q = 0.f;
    for (int gg = 0; gg < 8; ++gg) { s += buf[t * 8 + gg]; q += buf[1024 + t * 8 + gg]; }
    atomicAdd(&bn_sum[t], s);
    atomicAdd(&bn_sq[t], q);
  }
}

// ---------------- a2h split-K block (atomic XA) ----------------
constexpr int A2H_K = 3000, A2H_SPLIT = 200;
__device__ __forceinline__ void a2h_block(int rb, int sp, const float* __restrict__ A,
    const float* __restrict__ W, const float* __restrict__ bias, float* __restrict__ XA,
    float* xT) {
  constexpr int STR = 18;
  const int t = threadIdx.x;
  const int row0 = rb * 16;
  const int k0 = sp * A2H_SPLIT;
  for (int i = t; i < 16 * 50; i += 256) {
    const int r = i / 50, kq = i - r * 50;
    const float4 v = *(const float4*)&A[(long)(row0 + r) * A2H_K + k0 + kq * 4];
    xT[(kq * 4 + 0) * STR + r] = v.x;
    xT[(kq * 4 + 1) * STR + r] = v.y;
    xT[(kq * 4 + 2) * STR + r] = v.z;
    xT[(kq * 4 + 3) * STR + r] = v.w;
  }
  __syncthreads();
  const int rg = t >> 5, cg = t & 31;
  const int r0 = rg * 2, j0 = cg * 4;
  float acc[2][4];
  for (int r = 0; r < 2; ++r)
    for (int c = 0; c < 4; ++c) acc[r][c] = 0.f;
  const float* Wp = W + (long)k0 * HIDDEN + j0;
  for (int k = 0; k < A2H_SPLIT; ++k) {
    const float4 w = *(const float4*)&Wp[(long)k * HIDDEN];
    const float2 x = *(const float2*)&xT[k * STR + r0];
    const float wa[4] = {w.x, w.y, w.z, w.w};
    for (int c = 0; c < 4; ++c) {
      acc[0][c] = fmaf(x.x, wa[c], acc[0][c]);
      acc[1][c] = fmaf(x.y, wa[c], acc[1][c]);
    }
  }
  if (sp == 0)
    for (int c = 0; c < 4; ++c) { acc[0][c] += bias[j0 + c]; acc[1][c] += bias[j0 + c]; }
  for (int r = 0; r < 2; ++r)
    for (int c = 0; c < 4; ++c)
      atomicAdd(&XA[(size_t)(row0 + r0 + r) * HIDDEN + j0 + c], acc[r][c]);
}

// ---------------- conv block ----------------
__device__ __forceinline__ void conv_block(int g, const float* __restrict__ PS,
    const float* __restrict__ CK, const float* __restrict__ CB, float* __restrict__ XP,
    float* seq) {
  const int t = threadIdx.x;
  for (int i = t; i < 1000; i += 256) seq[i] = PS[g * 1000 + i];
  __syncthreads();
  const int pl = t & 31, cgp = t >> 5;
  float kr[4][8];
  for (int cc = 0; cc < 4; ++cc)
    for (int k = 0; k < 8; ++k) kr[cc][k] = CK[(cgp * 4 + cc) * 8 + k];
  float m[4] = {-1e30f, -1e30f, -1e30f, -1e30f};
  for (int i = 0; i < 32; ++i) {
    int p = pl + 32 * i;
    if (p < 993) {
      float sv[8];
      for (int k = 0; k < 8; ++k) sv[k] = seq[p + k];
      for (int cc = 0; cc < 4; ++cc) {
        float s = 0.f;
        for (int k = 0; k < 8; ++k) s = fmaf(sv[k], kr[cc][k], s);
        m[cc] = fmaxf(m[cc], s);
      }
    }
  }
  for (int off = 16; off >= 1; off >>= 1)
    for (int cc = 0; cc < 4; ++cc) m[cc] = fmaxf(m[cc], __shfl_xor(m[cc], off));
  if (pl == 0)
    for (int cc = 0; cc < 4; ++cc)
      XP[g * 32 + cgp * 4 + cc] = relu_f(m[cc] + CB[cgp * 4 + cc]);
}

// ---------------- fat0: gin0 (f16 Ylig walker) + a2h(sp 0-4) + conv ----------------
__global__ __launch_bounds__(256, 4) void fat0_kernel(
    const unsigned short* __restrict__ Ylig, unsigned short* __restrict__ Oh0,
    const int* __restrict__ row_ptr, const int* __restrict__ csr_src,
    const short* __restrict__ ws, const float* __restrict__ b1,
    const float* __restrict__ b2,
    float* __restrict__ bn_sum, float* __restrict__ bn_sq,
    const float* __restrict__ a2h, const float* __restrict__ a1W,
    const float* __restrict__ a1b, float* __restrict__ XA,
    const float* __restrict__ pseq, const float* __restrict__ convk,
    const float* __restrict__ convb, float* __restrict__ XP32) {
  __shared__ __align__(16) float buf[32 * STRK];
  const int b = blockIdx.x;
  if (b < NNODES / 32) {
    gin_block<80, 96, false>(b, Ylig, Oh0, row_ptr, csr_src,
                             ws, b1, ws + 24576, b2,
                             nullptr, nullptr, nullptr, nullptr,
                             bn_sum, bn_sq, buf);
  } else if (b < NNODES / 32 + (NGRAPHS / 16) * 5) {
    const int q = b - NNODES / 32;
    a2h_block(q & 127, q >> 7, a2h, a1W, a1b, XA, buf);
  } else {
    conv_block(b - (NNODES / 32 + (NGRAPHS / 16) * 5), pseq, convk, convb, XP32, buf);
  }
}

// ---------------- gin wrapper (layers 1,2) + a2h tail ----------------
__global__ __launch_bounds__(256, 4) void gin_kernel(
    const unsigned short* __restrict__ OhIn, unsigned short* __restrict__ OhOut,
    const int* __restrict__ row_ptr, const int* __restrict__ csr_src,
    const short* __restrict__ w1s, const float* __restrict__ b1,
    const short* __restrict__ w2s, const float* __restrict__ b2,
    const float* __restrict__ psum, const float* __restrict__ psq,
    const float* __restrict__ bg, const float* __restrict__ bb2,
    float* __restrict__ bn_sum, float* __restrict__ bn_sq,
    const float* __restrict__ a2h, const float* __restrict__ a1W,
    const float* __restrict__ a1b, float* __restrict__ XA, int sp_base) {
  __shared__ __align__(16) float buf[32 * STRK];
  const int b = blockIdx.x;
  if (b < NNODES / 32) {
    gin_block<128, 128, true>(b, OhIn, OhOut, row_ptr, csr_src,
                              w1s, b1, w2s, b2,
                              psum, psq, bg, bb2,
                              bn_sum, bn_sq, buf);
  } else {
    const int q = b - NNODES / 32;
    a2h_block(q & 127, sp_base + (q >> 7), a2h, a1W, a1b, XA, buf);
  }
}

// ---------------- mega-head ----------------
__global__ __launch_bounds__(256) void head_kernel(
    const unsigned short* __restrict__ Oh, const int* __restrict__ gp,
    const float* __restrict__ psum, const float* __restrict__ psq,
    const float* __restrict__ bg, const float* __restrict__ bb2,
    const float* __restrict__ XP32, const float* __restrict__ XA,
    const float* __restrict__ ligW, const float* __restrict__ ligb,
    const float* __restrict__ protW, const float* __restrict__ protb,
    const float* __restrict__ a2W, const float* __restrict__ a2b,
    const float* __restrict__ c1W, const float* __restrict__ c1b,
    const float* __restrict__ c2W, const float* __restrict__ c2b,
    const float* __restrict__ oW, const float* __restrict__ ob,
    float* __restrict__ out) {
  __shared__ float Ps[4][128];
  __shared__ float XAs[4][128];
  __shared__ float XPs[4][32];
  __shared__ float XCs[4][384];
  __shared__ float XC2s[4][256];
  __shared__ float XC3s[4][128];
  const int t = threadIdx.x;
  const int g0 = blockIdx.x * 4;

  // phase A: pool (inline BN of layer 2, f16 O) + stage XA(relu) / XP
  {
    const int sub = t >> 6, lane = t & 63;
    const int g = g0 + sub;
    const int f0 = lane, f1 = lane + 64;
    float mu0 = psum[f0] * (1.0f / NNODES);
    float va0 = fmaxf(psq[f0] * (1.0f / NNODES) - mu0 * mu0, 0.0f);
    float sc0 = bg[f0] / sqrtf(va0 + 1e-5f);
    float sh0 = bb2[f0] - mu0 * sc0;
    float mu1 = psum[f1] * (1.0f / NNODES);
    float va1 = fmaxf(psq[f1] * (1.0f / NNODES) - mu1 * mu1, 0.0f);
    float sc1 = bg[f1] / sqrtf(va1 + 1e-5f);
    float sh1 = bb2[f1] - mu1 * sc1;
    const int n0 = gp[g], n1 = gp[g + 1];
    float a0 = 0.f, a1 = 0.f;
    for (int n = n0; n < n1; ++n) {
      a0 += relu_f(fmaf(h2f(Oh[(size_t)n * HIDDEN + f0]), sc0, sh0));
      a1 += relu_f(fmaf(h2f(Oh[(size_t)n * HIDDEN + f1]), sc1, sh1));
    }
    Ps[sub][f0] = a0;
    Ps[sub][f1] = a1;
    for (int i = t; i < 512; i += 256) XAs[i >> 7][i & 127] = relu_f(XA[g0 * 128 + i]);
    for (int i = t; i < 128; i += 256) XPs[i >> 5][i & 31] = XP32[g0 * 32 + i];
  }
  __syncthreads();

  // phase B: lig / prot / a2 -> XCs
  {
    const int j = t & 127, pr = t >> 7;
    const int s0 = pr * 2, s1 = pr * 2 + 1;
    float L0 = ligb[j], L1 = L0;
    float A0 = a2b[j], A1 = A0;
    for (int k = 0; k < 128; ++k) {
      const float wl = ligW[k * 128 + j];
      const float wa = a2W[k * 128 + j];
      L0 = fmaf(Ps[s0][k], wl, L0); L1 = fmaf(Ps[s1][k], wl, L1);
      A0 = fmaf(XAs[s0][k], wa, A0); A1 = fmaf(XAs[s1][k], wa, A1);
    }
    float P0 = protb[j], P1 = P0;
    for (int k = 0; k < 32; ++k) {
      const float wp = protW[k * 128 + j];
      P0 = fmaf(XPs[s0][k], wp, P0); P1 = fmaf(XPs[s1][k], wp, P1);
    }
    XCs[s0][j] = relu_f(L0);        XCs[s1][j] = relu_f(L1);
    XCs[s0][128 + j] = relu_f(P0);  XCs[s1][128 + j] = relu_f(P1);
    XCs[s0][256 + j] = relu_f(A0);  XCs[s1][256 + j] = relu_f(A1);
  }
  __syncthreads();

  // phase C: c1 (384 -> 256)
  {
    const int j = t;
    float a[4];
    const float bv = c1b[j];
    for (int s = 0; s < 4; ++s) a[s] = bv;
    for (int k = 0; k < 384; ++k) {
      const float w = c1W[k * 256 + j];
      for (int s = 0; s < 4; ++s) a[s] = fmaf(XCs[s][k], w, a[s]);
    }
    for (int s = 0; s < 4; ++s) XC2s[s][j] = relu_f(a[s]);
  }
  __syncthreads();

  // phase D: c2 (256 -> 128)
  {
    const int j = t & 127, pr = t >> 7;
    const int s0 = pr * 2, s1 = pr * 2 + 1;
    float a0 = c2b[j], a1 = a0;
    for (int k = 0; k < 256; ++k) {
      const float w = c2W[k * 128 + j];
      a0 = fmaf(XC2s[s0][k], w, a0);
      a1 = fmaf(XC2s[s1][k], w, a1);
    }
    XC3s[s0][j] = relu_f(a0);
    XC3s[s1][j] = relu_f(a1);
  }
  __syncthreads();

  // phase E: out (128 -> 1)
  {
    const int w = t >> 6, lane = t & 63;
    float p = XC3s[w][lane] * oW[lane] + XC3s[w][lane + 64] * oW[lane + 64];
    for (int off = 32; off >= 1; off >>= 1) p += __shfl_down(p, off);
    if (lane == 0) out[g0 + w] = p + ob[0];
  }
}

extern "C" void kernel_launch(void* const* d_in, const int* in_sizes, int n_in,
                              void* d_out, int out_size, void* d_ws, size_t ws_size,
                              hipStream_t stream) {
  const float* x_lig = (const float*)d_in[0];
  const float* pseq  = (const float*)d_in[1];
  const float* a2h   = (const float*)d_in[2];
  const int*   ei    = (const int*)d_in[3];
  const int*   batch = (const int*)d_in[4];
  const float* ginW1[3] = {(const float*)d_in[5],  (const float*)d_in[11], (const float*)d_in[17]};
  const float* ginb1[3] = {(const float*)d_in[6],  (const float*)d_in[12], (const float*)d_in[18]};
  const float* ginW2[3] = {(const float*)d_in[7],  (const float*)d_in[13], (const float*)d_in[19]};
  const float* ginb2[3] = {(const float*)d_in[8],  (const float*)d_in[14], (const float*)d_in[20]};
  const float* bng[3]   = {(const float*)d_in[9],  (const float*)d_in[15], (const float*)d_in[21]};
  const float* bnb[3]   = {(const float*)d_in[10], (const float*)d_in[16], (const float*)d_in[22]};
  const float* ligW  = (const float*)d_in[23]; const float* ligb  = (const float*)d_in[24];
  const float* convk = (const float*)d_in[25]; const float* convb = (const float*)d_in[26];
  const float* protW = (const float*)d_in[27]; const float* protb = (const float*)d_in[28];
  const float* a1W   = (const float*)d_in[29]; const float* a1b   = (const float*)d_in[30];
  const float* a2W   = (const float*)d_in[31]; const float* a2b   = (const float*)d_in[32];
  const float* c1W   = (const float*)d_in[33]; const float* c1b   = (const float*)d_in[34];
  const float* c2W   = (const float*)d_in[35]; const float* c2b   = (const float*)d_in[36];
  const float* oW    = (const float*)d_in[37]; const float* ob    = (const float*)d_in[38];

  char* base = (char*)d_ws;
  size_t off = 0;
  auto alloc = [&](size_t bytes) -> char* {
    char* p = base + off;
    off = (off + bytes + 511) & ~size_t(511);
    return p;
  };
  int*   counts  = (int*)alloc(NNODES * 4);
  int*   gcounts = (int*)alloc(NGRAPHS * 4);
  float* bn_sum  = (float*)alloc(3 * 128 * 4);
  float* bn_sq   = (float*)alloc(3 * 128 * 4);
  float* XA      = (float*)alloc((size_t)NGRAPHS * HIDDEN * 4);
  const size_t zero_bytes = off;
  short* wsplit   = (short*)alloc(188416 * 2);
  int*   row_ptr  = (int*)alloc((NNODES + 1) * 4);
  int*   nxt      = (int*)alloc(NNODES * 4);
  int*   gptr     = (int*)alloc((NGRAPHS + 1) * 4);
  int*   bsumsA   = (int*)alloc(401 * 4);
  int*   bsumsB   = (int*)alloc(9 * 4);
  int*   csr_src  = (int*)alloc(NEDGES * 4);
  float* XP32     = (float*)alloc(NGRAPHS * 32 * 4);
  unsigned short* Ylig = (unsigned short*)alloc((size_t)NNODES * 80 * 2);
  unsigned short* Oh0  = (unsigned short*)alloc((size_t)NNODES * 128 * 2);
  unsigned short* Oh1  = (unsigned short*)alloc((size_t)NNODES * 128 * 2);
  (void)ws_size; (void)in_sizes; (void)n_in; (void)out_size;

  hipMemsetAsync(d_ws, 0, zero_bytes, stream);

  prep_kernel<<<NEDGES / 256 + NNODES / 256 + 736 + 8000, 256, 0, stream>>>(
      ei, batch, counts, gcounts, ginW1[0], ginW2[0], ginW1[1], ginW2[1],
      ginW1[2], ginW2[2], wsplit, x_lig, Ylig);
  scan_block2_kernel<<<NNODES / 256 + NGRAPHS / 256, 256, 0, stream>>>(
      counts, row_ptr, bsumsA, gcounts, gptr, bsumsB);
  scan_top2_kernel<<<2, 1024, 0, stream>>>(bsumsA, bsumsB);
  scan_add2_kernel<<<NNODES / 256 + NGRAPHS / 256, 256, 0, stream>>>(
      row_ptr, bsumsA, nxt, gptr, bsumsB);
  scatter_kernel<<<(NEDGES + 255) / 256, 256, 0, stream>>>(ei, nxt, csr_src);

  // layer 0: f16 Ylig walker (+ a2h sp 0-4 + conv)
  fat0_kernel<<<NNODES / 32 + (NGRAPHS / 16) * 5 + NGRAPHS, 256, 0, stream>>>(
      Ylig, Oh0, row_ptr, csr_src, wsplit, ginb1[0], ginb2[0],
      bn_sum, bn_sq, a2h, a1W, a1b, XA, pseq, convk, convb, XP32);

  // layer 1: gather f16 Oh0 (BN0 on consume) -> Oh1 (+ a2h sp 5-9)
  gin_kernel<<<NNODES / 32 + (NGRAPHS / 16) * 5, 256, 0, stream>>>(
      Oh0, Oh1, row_ptr, csr_src,
      wsplit + 57344, ginb1[1], wsplit + 90112, ginb2[1],
      bn_sum, bn_sq, bng[0], bnb[0],
      bn_sum + 128, bn_sq + 128, a2h, a1W, a1b, XA, 5);

  // layer 2: gather f16 Oh1 (BN1 on consume) -> Oh0 (+ a2h sp 10-14)
  gin_kernel<<<NNODES / 32 + (NGRAPHS / 16) * 5, 256, 0, stream>>>(
      Oh1, Oh0, row_ptr, csr_src,
      wsplit + 122880, ginb1[2], wsplit + 155648, ginb2[2],
      bn_sum + 128, bn_sq + 128, bng[1], bnb[1],
      bn_sum + 256, bn_sq + 256, a2h, a1W, a1b, XA, 10);

  head_kernel<<<NGRAPHS / 4, 256, 0, stream>>>(Oh0, gptr,
      bn_sum + 256, bn_sq + 256, bng[2], bnb[2], XP32, XA,
      ligW, ligb, protW, protb, a2W, a2b, c1W, c1b, c2W, c2b, oW, ob, (float*)d_out);
}